// Round 19
// baseline (157.354 us; speedup 1.0000x reference)
//
#include <hip/hip_runtime.h>
#include <stdint.h>
#include <stddef.h>

typedef __bf16 bf16;
typedef __bf16 bf16x4 __attribute__((ext_vector_type(4)));
typedef __bf16 bf16x8 __attribute__((ext_vector_type(8)));
typedef float  f32x4  __attribute__((ext_vector_type(4)));
typedef float  f32x16 __attribute__((ext_vector_type(16)));
typedef float  f32x4v __attribute__((ext_vector_type(4)));

// async global->LDS, 16B per lane, wave-uniform LDS base + lane*16
__device__ __forceinline__ void gload_lds16(const void* g, void* lds) {
  __builtin_amdgcn_global_load_lds(
      (__attribute__((address_space(1))) void*)(uintptr_t)g,
      (__attribute__((address_space(3))) void*)lds,
      16, 0, 0);
}

// ---------------- fused input prep (unchanged) ----------------

__global__ __launch_bounds__(256) void prep_inputs(
    const float* __restrict__ x,     bf16* __restrict__ xb,
    const float* __restrict__ w_in,  bf16* __restrict__ wint,
    const float* __restrict__ w_out, bf16* __restrict__ woutt)
{
  __shared__ bf16 tile[32][33];
  const int bid = blockIdx.x, tid = threadIdx.x;

  if (bid < 8192) {
    int i = bid * 1024 + tid * 4;
    f32x4v v = *reinterpret_cast<const f32x4v*>(x + i);
    bf16x4 o;
    o[0] = (bf16)v[0]; o[1] = (bf16)v[1]; o[2] = (bf16)v[2]; o[3] = (bf16)v[3];
    *reinterpret_cast<bf16x4*>(xb + i) = o;
    return;
  }

  const float* in; bf16* out; int R, C, c0, r0;
  if (bid < 11264) {
    int t = bid - 8192;
    in = w_in; out = wint; R = 1024; C = 3072;
    c0 = (t % 96) * 32; r0 = (t / 96) * 32;
  } else {
    int t = bid - 11264;
    in = w_out; out = woutt; R = 1024; C = 1024;
    c0 = (t % 32) * 32; r0 = (t / 32) * 32;
  }
  const int tx = tid & 31, ty = tid >> 5;
  #pragma unroll
  for (int i = ty; i < 32; i += 8)
    tile[i][tx] = (bf16)in[(size_t)(r0 + i) * C + (c0 + tx)];
  __syncthreads();
  #pragma unroll
  for (int i = ty; i < 32; i += 8)
    out[(size_t)(c0 + i) * R + (r0 + tx)] = tile[tx][i];
}

// ---------------- GEMM 128^2 (2-barrier, proven) -- GEMM2 ----------------

template <typename OT, bool BIAS>
__global__ __launch_bounds__(256) void gemm_abt(
    const bf16* __restrict__ A, const bf16* __restrict__ Bt,
    const float* __restrict__ bias, OT* __restrict__ C, int M, int N, int K)
{
  __shared__ bf16 As[128 * 64];
  __shared__ bf16 Bs[128 * 64];

  const int tid = threadIdx.x;
  const int w = tid >> 6, l = tid & 63;
  const int l15 = l & 15, l4 = l >> 4, l7 = l & 7;
  const int wr = w >> 1, wc = w & 1;

  const int nwgx = N >> 7;
  const int nwg  = (M >> 7) * nwgx;
  const int cpx  = nwg >> 3;
  const int bid  = blockIdx.x;
  const int swz  = (bid & 7) * cpx + (bid >> 3);
  const int m0 = (swz / nwgx) * 128, n0 = (swz % nwgx) * 128;

  f32x4 acc[4][4];
  #pragma unroll
  for (int i = 0; i < 4; i++)
    #pragma unroll
    for (int j = 0; j < 4; j++) acc[i][j] = (f32x4){0.f, 0.f, 0.f, 0.f};

  const int srow  = w * 8 + (l >> 3);
  const int sslot = (l & 7) ^ ((l >> 3) & 7);
  const int KT = K >> 6;

  for (int kt = 0; kt < KT; ++kt) {
    __syncthreads();
    const int kcol = kt * 64 + sslot * 8;
    #pragma unroll
    for (int p = 0; p < 4; ++p) {
      gload_lds16(A  + (size_t)(m0 + p * 32 + srow) * K + kcol,
                  (char*)As + p * 4096 + w * 1024);
      gload_lds16(Bt + (size_t)(n0 + p * 32 + srow) * K + kcol,
                  (char*)Bs + p * 4096 + w * 1024);
    }
    __syncthreads();

    #pragma unroll
    for (int kk = 0; kk < 2; ++kk) {
      const int coff = (kk * 32 + l4 * 8) ^ (l7 << 3);
      bf16x8 af[4], bq[4];
      #pragma unroll
      for (int m = 0; m < 4; ++m) {
        int r = wr * 64 + m * 16 + l15;
        af[m] = *reinterpret_cast<const bf16x8*>(&As[r * 64 + coff]);
      }
      #pragma unroll
      for (int n = 0; n < 4; ++n) {
        int r = wc * 64 + n * 16 + l15;
        bq[n] = *reinterpret_cast<const bf16x8*>(&Bs[r * 64 + coff]);
      }
      #pragma unroll
      for (int m = 0; m < 4; ++m)
        #pragma unroll
        for (int n = 0; n < 4; ++n)
          acc[m][n] = __builtin_amdgcn_mfma_f32_16x16x32_bf16(af[m], bq[n], acc[m][n], 0, 0, 0);
    }
  }

  #pragma unroll
  for (int m = 0; m < 4; ++m) {
    #pragma unroll
    for (int n = 0; n < 4; ++n) {
      int col = n0 + wc * 64 + n * 16 + l15;
      float bv = BIAS ? bias[col] : 0.f;
      #pragma unroll
      for (int j = 0; j < 4; ++j) {
        int row = m0 + wr * 64 + m * 16 + l4 * 4 + j;
        float v = acc[m][n][j] + bv;
        if constexpr (BIAS)
          __builtin_nontemporal_store((OT)v, &C[(size_t)row * N + col]);
        else
          C[(size_t)row * N + col] = (OT)v;
      }
    }
  }
}

// ---------------- GEMM 256^2 8-phase, quarter-unit counted-vmcnt -----------
// 512 thr = 8 waves (2 row x 4 col), wave output 128x64 (8x4 16x16 frags).
// 2 LDS buffers (K-step t in buf[t&1]). 8 phases per 2 K-steps; phase =
// {ds_read frags; stage 1 quarter-unit pair; [vmcnt]; s_barrier; setprio;
//  16 MFMA; setprio; s_barrier}. Quarter-units (64 rows, 1 load/thread)
// free at phase granularity: A-mh0 after ph0 (nh=1 reuses regs), A-mh1
// after ph2, B units after ph1 -> stage t+2 into the CURRENT buffer's
// freed regions. Stage slots / waits (derived, checked per unit):
//  ph0: A-Q1,Q3(t+1)        ph4: A-Q1,Q3(t+2)
//  ph1: A-Q0,Q2(t+2) vm(10) ph5: A-Q0,Q2(t+3) vm(10)
//  ph2: B-u01(t+2)          ph6: B-u01(t+3)
//  ph3: B-u23(t+2)  vm(8)   ph7: B-u23(t+3)  vm(8)
// Each vmcnt leaves 8-10 loads (4-5 phases of slack) in flight - NEVER
// drains (R9's mistake) - and certifies exactly the units read one phase
// later (R14's mistake was reading frags post-barrier + tight WAR windows).
// Raw s_barrier (memory clobber, no implicit vmcnt drain); compiler handles
// ds_read->MFMA lgkmcnt. Frag reads per phase: 12/4/8/0 (A cached across
// nh, B cached across mh).

template <typename OT, bool BIAS>
__global__ __launch_bounds__(512, 1) void gemm256p(
    const bf16* __restrict__ A,   // [M][K]
    const bf16* __restrict__ Bt,  // [N][K]
    const float* __restrict__ bias,
    OT* __restrict__ C, int M, int N, int K)
{
  __shared__ bf16 As[2][256 * 64];
  __shared__ bf16 Bs[2][256 * 64];

  const int tid = threadIdx.x;
  const int w = tid >> 6, l = tid & 63;
  const int l15 = l & 15, l4 = l >> 4, l7 = l & 7;
  const int wm = w >> 2, wn = w & 3;

  const int nwgx = N >> 8;
  const int nwg  = (M >> 8) * nwgx;
  const int cpx  = nwg >> 3;
  const int bid  = blockIdx.x;
  const int swz  = (bid & 7) * cpx + (bid >> 3);
  const int m0 = (swz / nwgx) * 256, n0 = (swz % nwgx) * 256;

  f32x4 acc[8][4];
  #pragma unroll
  for (int i = 0; i < 8; i++)
    #pragma unroll
    for (int j = 0; j < 4; j++) acc[i][j] = (f32x4){0.f, 0.f, 0.f, 0.f};

  const int w8l   = w * 8 + (l >> 3);            // staging row 0..63 in a unit
  const int sslot = (l & 7) ^ ((l >> 3) & 7);    // pre-swizzled 16B slot

  // stage one 64-row quarter-unit (1 load/thread)
  #define SA(t, q) gload_lds16(A  + (size_t)(m0 + (q) * 64 + w8l) * K + (t) * 64 + sslot * 8, \
                               (char*)As[(t) & 1] + (q) * 8192 + w * 1024)
  #define SB(t, u) gload_lds16(Bt + (size_t)(n0 + (u) * 64 + w8l) * K + (t) * 64 + sslot * 8, \
                               (char*)Bs[(t) & 1] + (u) * 8192 + w * 1024)
  #define BAR()  asm volatile("s_barrier" ::: "memory")
  #define VM(n)  asm volatile("s_waitcnt vmcnt(" #n ")" ::: "memory")

  bf16x8 afr[4][2], bfr[2][2][2];

  #define LDA(buf, mh)                                                          \
    _Pragma("unroll")                                                           \
    for (int i = 0; i < 4; ++i)                                                 \
      _Pragma("unroll")                                                         \
      for (int kk = 0; kk < 2; ++kk)                                            \
        afr[i][kk] = *reinterpret_cast<const bf16x8*>(                          \
            &As[buf][(wm * 128 + (mh) * 64 + i * 16 + l15) * 64 +               \
                     (((kk * 4 + l4) ^ l7) * 8)]);
  #define LDB(buf, nh)                                                          \
    _Pragma("unroll")                                                           \
    for (int n2 = 0; n2 < 2; ++n2)                                              \
      _Pragma("unroll")                                                         \
      for (int kk = 0; kk < 2; ++kk)                                            \
        bfr[nh][n2][kk] = *reinterpret_cast<const bf16x8*>(                     \
            &Bs[buf][(wn * 64 + (nh) * 32 + n2 * 16 + l15) * 64 +               \
                     (((kk * 4 + l4) ^ l7) * 8)]);
  #define MM(mh, nh)                                                            \
    __builtin_amdgcn_s_setprio(1);                                              \
    _Pragma("unroll")                                                           \
    for (int i = 0; i < 4; ++i)                                                 \
      _Pragma("unroll")                                                         \
      for (int n2 = 0; n2 < 2; ++n2)                                            \
        _Pragma("unroll")                                                       \
        for (int kk = 0; kk < 2; ++kk)                                          \
          acc[(mh) * 4 + i][(nh) * 2 + n2] =                                    \
              __builtin_amdgcn_mfma_f32_16x16x32_bf16(                          \
                  afr[i][kk], bfr[nh][n2][kk],                                  \
                  acc[(mh) * 4 + i][(nh) * 2 + n2], 0, 0, 0);                   \
    __builtin_amdgcn_s_setprio(0);

  // prologue: t=0 all 8 units, then t=1 partial (A-Q0,Q2 + B all)
  SA(0, 0); SA(0, 2); SA(0, 1); SA(0, 3);
  SB(0, 0); SB(0, 1); SB(0, 2); SB(0, 3);
  SA(1, 0); SA(1, 2);
  SB(1, 0); SB(1, 1); SB(1, 2); SB(1, 3);
  VM(6);                       // t=0's 8 units landed; t=1's 6 may fly
  BAR();

  for (int it = 0; it < 8; ++it) {
    const int t0 = 2 * it, t1 = 2 * it + 1;
    const bool more = (it < 7);
    // ph0: read buf0 (0,0); stage A-Q1,Q3(t1->buf1)
    LDA(0, 0); LDB(0, 0);
    SA(t1, 1); SA(t1, 3);
    BAR(); MM(0, 0) BAR();
    // ph1: read B-nh1; stage A-Q0,Q2(t0+2->buf0)
    LDB(0, 1);
    if (more) { SA(t0 + 2, 0); SA(t0 + 2, 2); }
    VM(10);
    BAR(); MM(0, 1) BAR();
    // ph2: read A-mh1; stage B-u01(t0+2)
    LDA(0, 1);
    if (more) { SB(t0 + 2, 0); SB(t0 + 2, 1); }
    BAR(); MM(1, 0) BAR();
    // ph3: stage B-u23(t0+2)
    if (more) { SB(t0 + 2, 2); SB(t0 + 2, 3); }
    VM(8);
    BAR(); MM(1, 1) BAR();
    // ph4: read buf1 (0,0); stage A-Q1,Q3(t0+2->buf0)
    LDA(1, 0); LDB(1, 0);
    if (more) { SA(t0 + 2, 1); SA(t0 + 2, 3); }
    BAR(); MM(0, 0) BAR();
    // ph5: stage A-Q0,Q2(t1+2->buf1)
    LDB(1, 1);
    if (more) { SA(t1 + 2, 0); SA(t1 + 2, 2); }
    VM(10);
    BAR(); MM(0, 1) BAR();
    // ph6: stage B-u01(t1+2)
    LDA(1, 1);
    if (more) { SB(t1 + 2, 0); SB(t1 + 2, 1); }
    BAR(); MM(1, 0) BAR();
    // ph7: stage B-u23(t1+2)
    if (more) { SB(t1 + 2, 2); SB(t1 + 2, 3); }
    VM(8);
    BAR(); MM(1, 1) BAR();
  }
  #undef SA
  #undef SB
  #undef BAR
  #undef VM
  #undef LDA
  #undef LDB
  #undef MM

  // epilogue: D[row][col], col = lane&15, row = (lane>>4)*4 + j
  #pragma unroll
  for (int mh = 0; mh < 2; ++mh)
    #pragma unroll
    for (int i = 0; i < 4; ++i)
      #pragma unroll
      for (int nh = 0; nh < 2; ++nh)
        #pragma unroll
        for (int n2 = 0; n2 < 2; ++n2) {
          int col = n0 + wn * 64 + nh * 32 + n2 * 16 + l15;
          float bv = BIAS ? bias[col] : 0.f;
          #pragma unroll
          for (int j = 0; j < 4; ++j) {
            int row = m0 + wm * 128 + mh * 64 + i * 16 + l4 * 4 + j;
            C[(size_t)row * N + col] = (OT)(acc[mh * 4 + i][nh * 2 + n2][j] + bv);
          }
        }
}

// ---------------- fused flash attention (unchanged R12/R18 optimum) --------

__global__ __launch_bounds__(512) void attn_fused(
    const bf16* __restrict__ qkv,
    bf16* __restrict__ aout)      // [8192][1024], col = h*64+d
{
  __shared__ bf16 Ks[64 * 64];
  __shared__ bf16 Vt[64 * 64];
  __shared__ bf16 Pl[8][32 * 64];

  const int tid = threadIdx.x;
  const int w = tid >> 6, l = tid & 63;
  const int l31 = l & 31, hi = l >> 5;

  const int bid = blockIdx.x;            // 512 blocks
  const int c  = bid & 7, rr = bid >> 3;
  const int g  = c * 16 + (rr & 15);
  const int qt = rr >> 4;
  const int h  = g & 15;
  const int b  = g >> 4;

  const bf16* base = qkv + (size_t)b * 1024 * 3072;
  const int qrow0 = qt * 256 + w * 32;

  const float qscale = 0.03125f * 1.44269504f;
  bf16x8 qf[4];
  #pragma unroll
  for (int st = 0; st < 4; st++) {
    const bf16* p = base + (size_t)(qrow0 + l31) * 3072 + h * 64 + st * 16 + hi * 8;
    bf16x8 v = *reinterpret_cast<const bf16x8*>(p);
    #pragma unroll
    for (int e = 0; e < 8; e++) v[e] = (bf16)((float)v[e] * qscale);
    qf[st] = v;
  }

  bf16x8 onesf;
  #pragma unroll
  for (int e = 0; e < 8; e++) onesf[e] = (bf16)1.0f;

  f32x16 acc0 = {}, acc1 = {}, accS = {};

  const int skey  = w * 8 + (l >> 3);
  const int sslot = (l & 7) ^ ((l >> 3) & 7);
  const int vd0   = (tid & 15) * 4;
  const int vk0   = ((tid >> 4) & 15) * 4;
  const int vslot = (tid >> 5) & 7;
  const int vhalf = (tid >> 4) & 1;

  for (int kt = 0; kt < 16; ++kt) {
    __syncthreads();
    gload_lds16(base + (size_t)(kt * 64 + skey) * 3072 + 1024 + h * 64 + sslot * 8,
                (char*)Ks + w * 1024);
    if (tid < 256) {
      bf16x4 vv[4];
      #pragma unroll
      for (int i = 0; i < 4; ++i)
        vv[i] = *reinterpret_cast<const bf16x4*>(
            base + (size_t)(kt * 64 + vk0 + i) * 3072 + 2048 + h * 64 + vd0);
      #pragma unroll
      for (int j = 0; j < 4; ++j) {
        int d = vd0 + j;
        bf16x4 o; o[0] = vv[0][j]; o[1] = vv[1][j]; o[2] = vv[2][j]; o[3] = vv[3][j];
        *reinterpret_cast<bf16x4*>(
            &Vt[d * 64 + ((vslot ^ (d & 7) ^ ((d >> 3) & 7)) * 8 + vhalf * 4)]) = o;
      }
    }
    __syncthreads();

    #pragma unroll
    for (int ktile = 0; ktile < 2; ++ktile) {
      f32x16 s = {};
      const int key = ktile * 32 + l31;
      #pragma unroll
      for (int st = 0; st < 4; ++st) {
        const int slot = (2 * st + hi) ^ (key & 7);
        bf16x8 kf = *reinterpret_cast<const bf16x8*>(&Ks[key * 64 + slot * 8]);
        s = __builtin_amdgcn_mfma_f32_32x32x16_bf16(kf, qf[st], s, 0, 0, 0);
      }
      #pragma unroll
      for (int gq = 0; gq < 4; ++gq) {
        bf16x4 pb;
        #pragma unroll
        for (int j2 = 0; j2 < 4; ++j2) {
          float pv = __builtin_amdgcn_exp2f(s[4 * gq + j2]);
          pb[j2] = (bf16)pv;
        }
        const int chunk = ktile * 4 + gq;
        *reinterpret_cast<bf16x4*>(
            &Pl[w][l31 * 64 + ((chunk ^ (l31 & 7)) * 8 + hi * 4)]) = pb;
      }
    }

    const int d7x0 = (l31 & 7) ^ (l31 >> 3);
    const int d7x1 = d7x0 ^ 4;
    #pragma unroll
    for (int st = 0; st < 4; ++st) {
      const int cs = 2 * st + hi;
      bf16x8 pa  = *reinterpret_cast<const bf16x8*>(
          &Pl[w][l31 * 64 + ((cs ^ (l31 & 7)) * 8)]);
      accS = __builtin_amdgcn_mfma_f32_32x32x16_bf16(pa, onesf, accS, 0, 0, 0);
      bf16x8 vf0 = *reinterpret_cast<const bf16x8*>(
          &Vt[l31 * 64 + ((cs ^ d7x0) * 8)]);
      acc0 = __builtin_amdgcn_mfma_f32_32x32x16_bf16(pa, vf0, acc0, 0, 0, 0);
      bf16x8 vf1 = *reinterpret_cast<const bf16x8*>(
          &Vt[(32 + l31) * 64 + ((cs ^ d7x1) * 8)]);
      acc1 = __builtin_amdgcn_mfma_f32_32x32x16_bf16(pa, vf1, acc1, 0, 0, 0);
    }
  }

  #pragma unroll
  for (int reg = 0; reg < 16; ++reg) {
    int q_r = (reg & 3) + 8 * (reg >> 2) + 4 * hi;
    float rinv = 1.0f / accS[reg];
    size_t rowoff = ((size_t)b * 1024 + qrow0 + q_r) * 1024 + h * 64;
    aout[rowoff + l31]      = (bf16)(acc0[reg] * rinv);
    aout[rowoff + 32 + l31] = (bf16)(acc1[reg] * rinv);
  }
}

// ---------------- launch ----------------

extern "C" void kernel_launch(void* const* d_in, const int* in_sizes, int n_in,
                              void* d_out, int out_size, void* d_ws, size_t ws_size,
                              hipStream_t stream) {
  const float* x     = (const float*)d_in[0];   // [8,1024,1024]
  const float* w_in  = (const float*)d_in[1];   // [1024,3072]
  const float* w_out = (const float*)d_in[2];   // [1024,1024]
  const float* b_out = (const float*)d_in[3];   // [1024]
  float* out = (float*)d_out;                   // [8,1024,1024] fp32

  bf16* xb    = (bf16*)d_ws;                         // 8192*1024
  bf16* wint  = xb    + (size_t)8192 * 1024;         // 3072*1024  (w_in^T)
  bf16* woutt = wint  + (size_t)3072 * 1024;         // 1024*1024  (w_out^T)
  bf16* qkv   = woutt + (size_t)1024 * 1024;         // 8192*3072
  bf16* ao    = qkv   + (size_t)8192 * 3072;         // 8192*1024

  // fused input prep
  prep_inputs<<<12288, 256, 0, stream>>>(x, xb, w_in, wint, w_out, woutt);

  // qkv = x @ w_in  - 256^2 8-phase counted-vmcnt, 384 blocks (32x12)
  gemm256p<bf16, false><<<384, 512, 0, stream>>>(xb, wint, nullptr, qkv, 8192, 3072, 1024);

  // fused attention -> ao
  attn_fused<<<512, 512, 0, stream>>>(qkv, ao);

  // out = ao @ w_out + b_out  - 128^2, 512 blocks, NT stores
  gemm_abt<float, true><<<512, 256, 0, stream>>>(ao, woutt, b_out, out, 8192, 1024, 1024);
}

// Round 20
// 156.358 us; speedup vs baseline: 1.0064x; 1.0064x over previous
//
#include <hip/hip_runtime.h>
#include <stdint.h>
#include <stddef.h>

typedef __bf16 bf16;
typedef __bf16 bf16x4 __attribute__((ext_vector_type(4)));
typedef __bf16 bf16x8 __attribute__((ext_vector_type(8)));
typedef float  f32x4  __attribute__((ext_vector_type(4)));
typedef float  f32x16 __attribute__((ext_vector_type(16)));
typedef float  f32x4v __attribute__((ext_vector_type(4)));

// async global->LDS, 16B per lane, wave-uniform LDS base + lane*16
__device__ __forceinline__ void gload_lds16(const void* g, void* lds) {
  __builtin_amdgcn_global_load_lds(
      (__attribute__((address_space(1))) void*)(uintptr_t)g,
      (__attribute__((address_space(3))) void*)lds,
      16, 0, 0);
}

// ---------------- fused input prep ----------------
// One kernel, blockIdx-range dispatch:
//  [0, 8192)        : x f32 -> bf16 (4 elem/thread)
//  [8192, 11264)    : w_in  [1024][3072] -> w_in^T  bf16 (32x32 tiles)
//  [11264, 12288)   : w_out [1024][1024] -> w_out^T bf16

__global__ __launch_bounds__(256) void prep_inputs(
    const float* __restrict__ x,     bf16* __restrict__ xb,
    const float* __restrict__ w_in,  bf16* __restrict__ wint,
    const float* __restrict__ w_out, bf16* __restrict__ woutt)
{
  __shared__ bf16 tile[32][33];
  const int bid = blockIdx.x, tid = threadIdx.x;

  if (bid < 8192) {
    int i = bid * 1024 + tid * 4;
    f32x4v v = *reinterpret_cast<const f32x4v*>(x + i);
    bf16x4 o;
    o[0] = (bf16)v[0]; o[1] = (bf16)v[1]; o[2] = (bf16)v[2]; o[3] = (bf16)v[3];
    *reinterpret_cast<bf16x4*>(xb + i) = o;
    return;
  }

  const float* in; bf16* out; int R, C, c0, r0;
  if (bid < 11264) {
    int t = bid - 8192;                 // 96 x 32 tiles
    in = w_in; out = wint; R = 1024; C = 3072;
    c0 = (t % 96) * 32; r0 = (t / 96) * 32;
  } else {
    int t = bid - 11264;                // 32 x 32 tiles
    in = w_out; out = woutt; R = 1024; C = 1024;
    c0 = (t % 32) * 32; r0 = (t / 32) * 32;
  }
  const int tx = tid & 31, ty = tid >> 5;
  #pragma unroll
  for (int i = ty; i < 32; i += 8)
    tile[i][tx] = (bf16)in[(size_t)(r0 + i) * C + (c0 + tx)];
  __syncthreads();
  #pragma unroll
  for (int i = ty; i < 32; i += 8)
    out[(size_t)(c0 + i) * R + (r0 + tx)] = tile[tx][i];
}

// ---------------- GEMM: C[M][N] = A[M][K] * Bt[N][K]^T (+bias) ----------------
// 128x128 tile, BK=64, 4 waves in 2x2, each wave 64x64 (4x4 16x16 fragments).
// Proven 2-barrier structure (67.2-67.6us GEMM1 / ~786 TF, bank conflicts 0).
// Deep-schedule ports CLOSED after 3 failures (R9 75.6 / R14 75.4 / R19 74.6):
// at 128KB LDS only 1 block/CU is resident, so per-phase barriers stall the
// whole CU regardless of vmcnt choreography; the 2-barrier 128^2 wins because
// 2+ co-resident blocks absorb each other's barrier drains (m114 overlap).
// BIAS path (GEMM2) uses non-temporal C stores: out is write-once.

template <typename OT, bool BIAS>
__global__ __launch_bounds__(256) void gemm_abt(
    const bf16* __restrict__ A,   // [M][K]
    const bf16* __restrict__ Bt,  // [N][K]
    const float* __restrict__ bias,
    OT* __restrict__ C, int M, int N, int K)
{
  __shared__ bf16 As[128 * 64];
  __shared__ bf16 Bs[128 * 64];

  const int tid = threadIdx.x;
  const int w = tid >> 6, l = tid & 63;
  const int l15 = l & 15, l4 = l >> 4, l7 = l & 7;
  const int wr = w >> 1, wc = w & 1;

  const int nwgx = N >> 7;
  const int nwg  = (M >> 7) * nwgx;
  const int cpx  = nwg >> 3;
  const int bid  = blockIdx.x;
  const int swz  = (bid & 7) * cpx + (bid >> 3);
  const int m0 = (swz / nwgx) * 128, n0 = (swz % nwgx) * 128;

  f32x4 acc[4][4];
  #pragma unroll
  for (int i = 0; i < 4; i++)
    #pragma unroll
    for (int j = 0; j < 4; j++) acc[i][j] = (f32x4){0.f, 0.f, 0.f, 0.f};

  const int srow  = w * 8 + (l >> 3);
  const int sslot = (l & 7) ^ ((l >> 3) & 7);
  const int KT = K >> 6;

  for (int kt = 0; kt < KT; ++kt) {
    __syncthreads();
    const int kcol = kt * 64 + sslot * 8;
    #pragma unroll
    for (int p = 0; p < 4; ++p) {
      gload_lds16(A  + (size_t)(m0 + p * 32 + srow) * K + kcol,
                  (char*)As + p * 4096 + w * 1024);
      gload_lds16(Bt + (size_t)(n0 + p * 32 + srow) * K + kcol,
                  (char*)Bs + p * 4096 + w * 1024);
    }
    __syncthreads();

    #pragma unroll
    for (int kk = 0; kk < 2; ++kk) {
      const int coff = (kk * 32 + l4 * 8) ^ (l7 << 3);
      bf16x8 af[4], bq[4];
      #pragma unroll
      for (int m = 0; m < 4; ++m) {
        int r = wr * 64 + m * 16 + l15;
        af[m] = *reinterpret_cast<const bf16x8*>(&As[r * 64 + coff]);
      }
      #pragma unroll
      for (int n = 0; n < 4; ++n) {
        int r = wc * 64 + n * 16 + l15;
        bq[n] = *reinterpret_cast<const bf16x8*>(&Bs[r * 64 + coff]);
      }
      #pragma unroll
      for (int m = 0; m < 4; ++m)
        #pragma unroll
        for (int n = 0; n < 4; ++n)
          acc[m][n] = __builtin_amdgcn_mfma_f32_16x16x32_bf16(af[m], bq[n], acc[m][n], 0, 0, 0);
    }
  }

  #pragma unroll
  for (int m = 0; m < 4; ++m) {
    #pragma unroll
    for (int n = 0; n < 4; ++n) {
      int col = n0 + wc * 64 + n * 16 + l15;
      float bv = BIAS ? bias[col] : 0.f;
      #pragma unroll
      for (int j = 0; j < 4; ++j) {
        int row = m0 + wr * 64 + m * 16 + l4 * 4 + j;
        float v = acc[m][n][j] + bv;
        if constexpr (BIAS)
          __builtin_nontemporal_store((OT)v, &C[(size_t)row * N + col]);
        else
          C[(size_t)row * N + col] = (OT)v;
      }
    }
  }
}

// ---------------- fused flash attention (32x32x16, 8-wave shared K/V) ------
// EXACT R12/R16/R18 structure - the measured optimum (twice reproduced at
// ~156.4us total). Restructure scorecard on this kernel: dbuf (R7), in-reg
// P (R6), setprio (R10), V-prefetch (R15), KVBLK=128 (R17) - all negative.
// Occupancy-bound (VGPR 80, 3 blocks/CU at 48KB LDS), short dependency
// chains; keep it lean. Key techniques: fixed-shift softmax (|s|<~2, exact
// by shift invariance, scale*log2e folded into Q), swapped QK^T (32x32x16),
// P via per-wave LDS with XOR slot swizzle, V quad-transpose staging with
// write/read-paired swizzle, row-sums via ones-B MFMA (denominators match
// PV's bf16 P exactly), single v_exp_f32 per element via exp2 builtin.

__global__ __launch_bounds__(512) void attn_fused(
    const bf16* __restrict__ qkv,
    bf16* __restrict__ aout)      // [8192][1024], col = h*64+d
{
  __shared__ bf16 Ks[64 * 64];      // [key][d], source-swizzled 16B slots
  __shared__ bf16 Vt[64 * 64];      // [d][key], slot = c ^ (d&7) ^ ((d>>3)&7)
  __shared__ bf16 Pl[8][32 * 64];   // per-wave P [q][key], slot = c ^ (q&7)

  const int tid = threadIdx.x;
  const int w = tid >> 6, l = tid & 63;
  const int l31 = l & 31, hi = l >> 5;

  // XCD-grouped swizzle: batch b lands entirely on XCD b (K/V L2 reuse)
  const int bid = blockIdx.x;            // 512 blocks
  const int c  = bid & 7, rr = bid >> 3;
  const int g  = c * 16 + (rr & 15);     // 0..127 = b*16+h
  const int qt = rr >> 4;                // 0..3
  const int h  = g & 15;
  const int b  = g >> 4;

  const bf16* base = qkv + (size_t)b * 1024 * 3072;
  const int qrow0 = qt * 256 + w * 32;

  const float qscale = 0.03125f * 1.44269504f;   // D^-0.5 * log2(e)
  bf16x8 qf[4];
  #pragma unroll
  for (int st = 0; st < 4; st++) {
    const bf16* p = base + (size_t)(qrow0 + l31) * 3072 + h * 64 + st * 16 + hi * 8;
    bf16x8 v = *reinterpret_cast<const bf16x8*>(p);
    #pragma unroll
    for (int e = 0; e < 8; e++) v[e] = (bf16)((float)v[e] * qscale);
    qf[st] = v;
  }

  bf16x8 onesf;
  #pragma unroll
  for (int e = 0; e < 8; e++) onesf[e] = (bf16)1.0f;

  f32x16 acc0 = {}, acc1 = {}, accS = {};

  const int skey  = w * 8 + (l >> 3);            // wave w stages rows w*8..w*8+7
  const int sslot = (l & 7) ^ ((l >> 3) & 7);
  const int vd0   = (tid & 15) * 4;
  const int vk0   = ((tid >> 4) & 15) * 4;
  const int vslot = (tid >> 5) & 7;
  const int vhalf = (tid >> 4) & 1;

  for (int kt = 0; kt < 16; ++kt) {
    __syncthreads();
    gload_lds16(base + (size_t)(kt * 64 + skey) * 3072 + 1024 + h * 64 + sslot * 8,
                (char*)Ks + w * 1024);
    if (tid < 256) {
      bf16x4 vv[4];
      #pragma unroll
      for (int i = 0; i < 4; ++i)
        vv[i] = *reinterpret_cast<const bf16x4*>(
            base + (size_t)(kt * 64 + vk0 + i) * 3072 + 2048 + h * 64 + vd0);
      #pragma unroll
      for (int j = 0; j < 4; ++j) {
        int d = vd0 + j;
        bf16x4 o; o[0] = vv[0][j]; o[1] = vv[1][j]; o[2] = vv[2][j]; o[3] = vv[3][j];
        *reinterpret_cast<bf16x4*>(
            &Vt[d * 64 + ((vslot ^ (d & 7) ^ ((d >> 3) & 7)) * 8 + vhalf * 4)]) = o;
      }
    }
    __syncthreads();

    #pragma unroll
    for (int ktile = 0; ktile < 2; ++ktile) {
      f32x16 s = {};
      const int key = ktile * 32 + l31;
      #pragma unroll
      for (int st = 0; st < 4; ++st) {
        const int slot = (2 * st + hi) ^ (key & 7);
        bf16x8 kf = *reinterpret_cast<const bf16x8*>(&Ks[key * 64 + slot * 8]);
        s = __builtin_amdgcn_mfma_f32_32x32x16_bf16(kf, qf[st], s, 0, 0, 0);
      }
      #pragma unroll
      for (int gq = 0; gq < 4; ++gq) {
        bf16x4 pb;
        #pragma unroll
        for (int j2 = 0; j2 < 4; ++j2) {
          float pv = __builtin_amdgcn_exp2f(s[4 * gq + j2]);
          pb[j2] = (bf16)pv;
        }
        const int chunk = ktile * 4 + gq;
        *reinterpret_cast<bf16x4*>(
            &Pl[w][l31 * 64 + ((chunk ^ (l31 & 7)) * 8 + hi * 4)]) = pb;
      }
    }

    const int d7x0 = (l31 & 7) ^ (l31 >> 3);
    const int d7x1 = d7x0 ^ 4;
    #pragma unroll
    for (int st = 0; st < 4; ++st) {
      const int cs = 2 * st + hi;
      bf16x8 pa  = *reinterpret_cast<const bf16x8*>(
          &Pl[w][l31 * 64 + ((cs ^ (l31 & 7)) * 8)]);
      accS = __builtin_amdgcn_mfma_f32_32x32x16_bf16(pa, onesf, accS, 0, 0, 0);
      bf16x8 vf0 = *reinterpret_cast<const bf16x8*>(
          &Vt[l31 * 64 + ((cs ^ d7x0) * 8)]);
      acc0 = __builtin_amdgcn_mfma_f32_32x32x16_bf16(pa, vf0, acc0, 0, 0, 0);
      bf16x8 vf1 = *reinterpret_cast<const bf16x8*>(
          &Vt[(32 + l31) * 64 + ((cs ^ d7x1) * 8)]);
      acc1 = __builtin_amdgcn_mfma_f32_32x32x16_bf16(pa, vf1, acc1, 0, 0, 0);
    }
  }

  #pragma unroll
  for (int reg = 0; reg < 16; ++reg) {
    int q_r = (reg & 3) + 8 * (reg >> 2) + 4 * hi;
    float rinv = 1.0f / accS[reg];
    size_t rowoff = ((size_t)b * 1024 + qrow0 + q_r) * 1024 + h * 64;
    aout[rowoff + l31]      = (bf16)(acc0[reg] * rinv);
    aout[rowoff + 32 + l31] = (bf16)(acc1[reg] * rinv);
  }
}

// ---------------- launch ----------------

extern "C" void kernel_launch(void* const* d_in, const int* in_sizes, int n_in,
                              void* d_out, int out_size, void* d_ws, size_t ws_size,
                              hipStream_t stream) {
  const float* x     = (const float*)d_in[0];   // [8,1024,1024]
  const float* w_in  = (const float*)d_in[1];   // [1024,3072]
  const float* w_out = (const float*)d_in[2];   // [1024,1024]
  const float* b_out = (const float*)d_in[3];   // [1024]
  float* out = (float*)d_out;                   // [8,1024,1024] fp32

  bf16* xb    = (bf16*)d_ws;                         // 8192*1024
  bf16* wint  = xb    + (size_t)8192 * 1024;         // 3072*1024  (w_in^T)
  bf16* woutt = wint  + (size_t)3072 * 1024;         // 1024*1024  (w_out^T)
  bf16* qkv   = woutt + (size_t)1024 * 1024;         // 8192*3072
  bf16* ao    = qkv   + (size_t)8192 * 3072;         // 8192*1024

  // fused input prep: x->bf16 + w_in^T + w_out^T in one launch
  prep_inputs<<<12288, 256, 0, stream>>>(x, xb, w_in, wint, w_out, woutt);

  // qkv = x @ w_in   (bf16 out) - 128^2, 1536 blocks, XCD-chunked swizzle
  gemm_abt<bf16, false><<<1536, 256, 0, stream>>>(xb, wint, nullptr, qkv, 8192, 3072, 1024);

  // fused attention -> ao (bf16, [token][h*64+d]) - 8-wave blocks, 512 total
  attn_fused<<<512, 512, 0, stream>>>(qkv, ao);

  // out = ao @ w_out + b_out   (fp32 out) - 128^2, 512 blocks, NT stores
  gemm_abt<float, true><<<512, 256, 0, stream>>>(ao, woutt, b_out, out, 8192, 1024, 1024);
}

// Round 21
// 153.827 us; speedup vs baseline: 1.0229x; 1.0165x over previous
//
#include <hip/hip_runtime.h>
#include <stdint.h>
#include <stddef.h>

typedef __bf16 bf16;
typedef __bf16 bf16x4 __attribute__((ext_vector_type(4)));
typedef __bf16 bf16x8 __attribute__((ext_vector_type(8)));
typedef float  f32x4  __attribute__((ext_vector_type(4)));
typedef float  f32x16 __attribute__((ext_vector_type(16)));
typedef float  f32x4v __attribute__((ext_vector_type(4)));

// async global->LDS, 16B per lane, wave-uniform LDS base + lane*16
__device__ __forceinline__ void gload_lds16(const void* g, void* lds) {
  __builtin_amdgcn_global_load_lds(
      (__attribute__((address_space(1))) void*)(uintptr_t)g,
      (__attribute__((address_space(3))) void*)lds,
      16, 0, 0);
}

// ---------------- fused input prep ----------------
// One kernel, blockIdx-range dispatch:
//  [0, 8192)        : x f32 -> bf16 (4 elem/thread)
//  [8192, 11264)    : w_in  [1024][3072] -> w_in^T  bf16 (32x32 tiles)
//  [11264, 12288)   : w_out [1024][1024] -> w_out^T bf16

__global__ __launch_bounds__(256) void prep_inputs(
    const float* __restrict__ x,     bf16* __restrict__ xb,
    const float* __restrict__ w_in,  bf16* __restrict__ wint,
    const float* __restrict__ w_out, bf16* __restrict__ woutt)
{
  __shared__ bf16 tile[32][33];
  const int bid = blockIdx.x, tid = threadIdx.x;

  if (bid < 8192) {
    int i = bid * 1024 + tid * 4;
    f32x4v v = *reinterpret_cast<const f32x4v*>(x + i);
    bf16x4 o;
    o[0] = (bf16)v[0]; o[1] = (bf16)v[1]; o[2] = (bf16)v[2]; o[3] = (bf16)v[3];
    *reinterpret_cast<bf16x4*>(xb + i) = o;
    return;
  }

  const float* in; bf16* out; int R, C, c0, r0;
  if (bid < 11264) {
    int t = bid - 8192;                 // 96 x 32 tiles
    in = w_in; out = wint; R = 1024; C = 3072;
    c0 = (t % 96) * 32; r0 = (t / 96) * 32;
  } else {
    int t = bid - 11264;                // 32 x 32 tiles
    in = w_out; out = woutt; R = 1024; C = 1024;
    c0 = (t % 32) * 32; r0 = (t / 32) * 32;
  }
  const int tx = tid & 31, ty = tid >> 5;
  #pragma unroll
  for (int i = ty; i < 32; i += 8)
    tile[i][tx] = (bf16)in[(size_t)(r0 + i) * C + (c0 + tx)];
  __syncthreads();
  #pragma unroll
  for (int i = ty; i < 32; i += 8)
    out[(size_t)(c0 + i) * R + (r0 + tx)] = tile[tx][i];
}

// ---------------- GEMM: C[M][N] = A[M][K] * Bt[N][K]^T (+bias) ----------------
// 128x128 tile, BK=64, 4 waves in 2x2, each wave 64x64 (4x4 16x16 fragments).
// Proven 2-barrier structure (67.2-67.6us GEMM1 / ~786 TF, bank conflicts 0).
// Deep-schedule ports CLOSED after 3 failures (R9/R14/R19, all ~75us):
// at 128KB LDS only 1 block/CU is resident, so per-phase barriers stall the
// whole CU; the 2-barrier 128^2 wins because 2+ co-resident blocks absorb
// each other's barrier drains (m114 overlap).
// NEW (R21): L2-fitting supertile order inside each XCD chunk for GEMM1's
// shape (nwgx==24): 4-row x 6-col supertiles -> working set 10 panels
// (2.5MB) <= 4MB L2 (was 8 rows x 24 cols = 8MB, thrashing). Staging loads
// hit L2 (~200cy) instead of HBM (~900cy) inside the exposed vmcnt drain.
// BIAS path (GEMM2) keeps linear chunk order + non-temporal C stores.

template <typename OT, bool BIAS>
__global__ __launch_bounds__(256) void gemm_abt(
    const bf16* __restrict__ A,   // [M][K]
    const bf16* __restrict__ Bt,  // [N][K]
    const float* __restrict__ bias,
    OT* __restrict__ C, int M, int N, int K)
{
  __shared__ bf16 As[128 * 64];
  __shared__ bf16 Bs[128 * 64];

  const int tid = threadIdx.x;
  const int w = tid >> 6, l = tid & 63;
  const int l15 = l & 15, l4 = l >> 4, l7 = l & 7;
  const int wr = w >> 1, wc = w & 1;

  // XCD-chunked swizzle (grid%8==0, bijective). For GEMM1's shape, add a
  // 4x6 supertile order within the chunk (verified bijection: chunk = 8
  // supertiles x 24 tiles; rows c*8+str*4+t/6, cols stc*6+t%6).
  const int nwgx = N >> 7;
  const int nwg  = (M >> 7) * nwgx;
  const int cpx  = nwg >> 3;
  const int bid  = blockIdx.x;
  const int cch  = bid & 7, lid = bid >> 3;
  int mrow, ncol;
  if (nwgx == 24) {                      // GEMM1: 64x24 grid, rc=8 per chunk
    const int st = lid / 24, t = lid % 24;
    mrow = cch * 8 + (st >> 2) * 4 + t / 6;
    ncol = (st & 3) * 6 + t % 6;
  } else {                               // GEMM2: proven linear chunk order
    const int swz = cch * cpx + lid;
    mrow = swz / nwgx; ncol = swz % nwgx;
  }
  const int m0 = mrow * 128, n0 = ncol * 128;

  f32x4 acc[4][4];
  #pragma unroll
  for (int i = 0; i < 4; i++)
    #pragma unroll
    for (int j = 0; j < 4; j++) acc[i][j] = (f32x4){0.f, 0.f, 0.f, 0.f};

  const int srow  = w * 8 + (l >> 3);
  const int sslot = (l & 7) ^ ((l >> 3) & 7);
  const int KT = K >> 6;

  for (int kt = 0; kt < KT; ++kt) {
    __syncthreads();
    const int kcol = kt * 64 + sslot * 8;
    #pragma unroll
    for (int p = 0; p < 4; ++p) {
      gload_lds16(A  + (size_t)(m0 + p * 32 + srow) * K + kcol,
                  (char*)As + p * 4096 + w * 1024);
      gload_lds16(Bt + (size_t)(n0 + p * 32 + srow) * K + kcol,
                  (char*)Bs + p * 4096 + w * 1024);
    }
    __syncthreads();

    #pragma unroll
    for (int kk = 0; kk < 2; ++kk) {
      const int coff = (kk * 32 + l4 * 8) ^ (l7 << 3);
      bf16x8 af[4], bq[4];
      #pragma unroll
      for (int m = 0; m < 4; ++m) {
        int r = wr * 64 + m * 16 + l15;
        af[m] = *reinterpret_cast<const bf16x8*>(&As[r * 64 + coff]);
      }
      #pragma unroll
      for (int n = 0; n < 4; ++n) {
        int r = wc * 64 + n * 16 + l15;
        bq[n] = *reinterpret_cast<const bf16x8*>(&Bs[r * 64 + coff]);
      }
      #pragma unroll
      for (int m = 0; m < 4; ++m)
        #pragma unroll
        for (int n = 0; n < 4; ++n)
          acc[m][n] = __builtin_amdgcn_mfma_f32_16x16x32_bf16(af[m], bq[n], acc[m][n], 0, 0, 0);
    }
  }

  #pragma unroll
  for (int m = 0; m < 4; ++m) {
    #pragma unroll
    for (int n = 0; n < 4; ++n) {
      int col = n0 + wc * 64 + n * 16 + l15;
      float bv = BIAS ? bias[col] : 0.f;
      #pragma unroll
      for (int j = 0; j < 4; ++j) {
        int row = m0 + wr * 64 + m * 16 + l4 * 4 + j;
        float v = acc[m][n][j] + bv;
        if constexpr (BIAS)
          __builtin_nontemporal_store((OT)v, &C[(size_t)row * N + col]);
        else
          C[(size_t)row * N + col] = (OT)v;
      }
    }
  }
}

// ---------------- fused flash attention (32x32x16, 8-wave shared K/V) ------
// EXACT R12/R16/R18/R20 structure - the measured optimum (3x reproduced at
// ~156.4us total). Restructure scorecard: dbuf (R7), in-reg P (R6), setprio
// (R10), V-prefetch (R15), KVBLK=128 (R17) - all negative. Occupancy-bound
// (VGPR 80, 3 blocks/CU at 48KB LDS); keep registers lean.

__global__ __launch_bounds__(512) void attn_fused(
    const bf16* __restrict__ qkv,
    bf16* __restrict__ aout)      // [8192][1024], col = h*64+d
{
  __shared__ bf16 Ks[64 * 64];      // [key][d], source-swizzled 16B slots
  __shared__ bf16 Vt[64 * 64];      // [d][key], slot = c ^ (d&7) ^ ((d>>3)&7)
  __shared__ bf16 Pl[8][32 * 64];   // per-wave P [q][key], slot = c ^ (q&7)

  const int tid = threadIdx.x;
  const int w = tid >> 6, l = tid & 63;
  const int l31 = l & 31, hi = l >> 5;

  // XCD-grouped swizzle: batch b lands entirely on XCD b (K/V L2 reuse)
  const int bid = blockIdx.x;            // 512 blocks
  const int c  = bid & 7, rr = bid >> 3;
  const int g  = c * 16 + (rr & 15);     // 0..127 = b*16+h
  const int qt = rr >> 4;                // 0..3
  const int h  = g & 15;
  const int b  = g >> 4;

  const bf16* base = qkv + (size_t)b * 1024 * 3072;
  const int qrow0 = qt * 256 + w * 32;

  const float qscale = 0.03125f * 1.44269504f;   // D^-0.5 * log2(e)
  bf16x8 qf[4];
  #pragma unroll
  for (int st = 0; st < 4; st++) {
    const bf16* p = base + (size_t)(qrow0 + l31) * 3072 + h * 64 + st * 16 + hi * 8;
    bf16x8 v = *reinterpret_cast<const bf16x8*>(p);
    #pragma unroll
    for (int e = 0; e < 8; e++) v[e] = (bf16)((float)v[e] * qscale);
    qf[st] = v;
  }

  bf16x8 onesf;
  #pragma unroll
  for (int e = 0; e < 8; e++) onesf[e] = (bf16)1.0f;

  f32x16 acc0 = {}, acc1 = {}, accS = {};

  const int skey  = w * 8 + (l >> 3);            // wave w stages rows w*8..w*8+7
  const int sslot = (l & 7) ^ ((l >> 3) & 7);
  const int vd0   = (tid & 15) * 4;
  const int vk0   = ((tid >> 4) & 15) * 4;
  const int vslot = (tid >> 5) & 7;
  const int vhalf = (tid >> 4) & 1;

  for (int kt = 0; kt < 16; ++kt) {
    __syncthreads();
    gload_lds16(base + (size_t)(kt * 64 + skey) * 3072 + 1024 + h * 64 + sslot * 8,
                (char*)Ks + w * 1024);
    if (tid < 256) {
      bf16x4 vv[4];
      #pragma unroll
      for (int i = 0; i < 4; ++i)
        vv[i] = *reinterpret_cast<const bf16x4*>(
            base + (size_t)(kt * 64 + vk0 + i) * 3072 + 2048 + h * 64 + vd0);
      #pragma unroll
      for (int j = 0; j < 4; ++j) {
        int d = vd0 + j;
        bf16x4 o; o[0] = vv[0][j]; o[1] = vv[1][j]; o[2] = vv[2][j]; o[3] = vv[3][j];
        *reinterpret_cast<bf16x4*>(
            &Vt[d * 64 + ((vslot ^ (d & 7) ^ ((d >> 3) & 7)) * 8 + vhalf * 4)]) = o;
      }
    }
    __syncthreads();

    #pragma unroll
    for (int ktile = 0; ktile < 2; ++ktile) {
      f32x16 s = {};
      const int key = ktile * 32 + l31;
      #pragma unroll
      for (int st = 0; st < 4; ++st) {
        const int slot = (2 * st + hi) ^ (key & 7);
        bf16x8 kf = *reinterpret_cast<const bf16x8*>(&Ks[key * 64 + slot * 8]);
        s = __builtin_amdgcn_mfma_f32_32x32x16_bf16(kf, qf[st], s, 0, 0, 0);
      }
      #pragma unroll
      for (int gq = 0; gq < 4; ++gq) {
        bf16x4 pb;
        #pragma unroll
        for (int j2 = 0; j2 < 4; ++j2) {
          float pv = __builtin_amdgcn_exp2f(s[4 * gq + j2]);
          pb[j2] = (bf16)pv;
        }
        const int chunk = ktile * 4 + gq;
        *reinterpret_cast<bf16x4*>(
            &Pl[w][l31 * 64 + ((chunk ^ (l31 & 7)) * 8 + hi * 4)]) = pb;
      }
    }

    const int d7x0 = (l31 & 7) ^ (l31 >> 3);
    const int d7x1 = d7x0 ^ 4;
    #pragma unroll
    for (int st = 0; st < 4; ++st) {
      const int cs = 2 * st + hi;
      bf16x8 pa  = *reinterpret_cast<const bf16x8*>(
          &Pl[w][l31 * 64 + ((cs ^ (l31 & 7)) * 8)]);
      accS = __builtin_amdgcn_mfma_f32_32x32x16_bf16(pa, onesf, accS, 0, 0, 0);
      bf16x8 vf0 = *reinterpret_cast<const bf16x8*>(
          &Vt[l31 * 64 + ((cs ^ d7x0) * 8)]);
      acc0 = __builtin_amdgcn_mfma_f32_32x32x16_bf16(pa, vf0, acc0, 0, 0, 0);
      bf16x8 vf1 = *reinterpret_cast<const bf16x8*>(
          &Vt[(32 + l31) * 64 + ((cs ^ d7x1) * 8)]);
      acc1 = __builtin_amdgcn_mfma_f32_32x32x16_bf16(pa, vf1, acc1, 0, 0, 0);
    }
  }

  #pragma unroll
  for (int reg = 0; reg < 16; ++reg) {
    int q_r = (reg & 3) + 8 * (reg >> 2) + 4 * hi;
    float rinv = 1.0f / accS[reg];
    size_t rowoff = ((size_t)b * 1024 + qrow0 + q_r) * 1024 + h * 64;
    aout[rowoff + l31]      = (bf16)(acc0[reg] * rinv);
    aout[rowoff + 32 + l31] = (bf16)(acc1[reg] * rinv);
  }
}

// ---------------- launch ----------------

extern "C" void kernel_launch(void* const* d_in, const int* in_sizes, int n_in,
                              void* d_out, int out_size, void* d_ws, size_t ws_size,
                              hipStream_t stream) {
  const float* x     = (const float*)d_in[0];   // [8,1024,1024]
  const float* w_in  = (const float*)d_in[1];   // [1024,3072]
  const float* w_out = (const float*)d_in[2];   // [1024,1024]
  const float* b_out = (const float*)d_in[3];   // [1024]
  float* out = (float*)d_out;                   // [8,1024,1024] fp32

  bf16* xb    = (bf16*)d_ws;                         // 8192*1024
  bf16* wint  = xb    + (size_t)8192 * 1024;         // 3072*1024  (w_in^T)
  bf16* woutt = wint  + (size_t)3072 * 1024;         // 1024*1024  (w_out^T)
  bf16* qkv   = woutt + (size_t)1024 * 1024;         // 8192*3072
  bf16* ao    = qkv   + (size_t)8192 * 3072;         // 8192*1024

  // fused input prep: x->bf16 + w_in^T + w_out^T in one launch
  prep_inputs<<<12288, 256, 0, stream>>>(x, xb, w_in, wint, w_out, woutt);

  // qkv = x @ w_in   (bf16 out) - 128^2, 1536 blocks, supertiled XCD swizzle
  gemm_abt<bf16, false><<<1536, 256, 0, stream>>>(xb, wint, nullptr, qkv, 8192, 3072, 1024);

  // fused attention -> ao (bf16, [token][h*64+d]) - 8-wave blocks, 512 total
  attn_fused<<<512, 512, 0, stream>>>(qkv, ao);

  // out = ao @ w_out + b_out   (fp32 out) - 128^2, 512 blocks, NT stores
  gemm_abt<float, true><<<512, 256, 0, stream>>>(ao, woutt, b_out, out, 8192, 1024, 1024);
}

// Round 22
// 153.416 us; speedup vs baseline: 1.0257x; 1.0027x over previous
//
#include <hip/hip_runtime.h>
#include <stdint.h>
#include <stddef.h>

typedef __bf16 bf16;
typedef __bf16 bf16x4 __attribute__((ext_vector_type(4)));
typedef __bf16 bf16x8 __attribute__((ext_vector_type(8)));
typedef float  f32x4  __attribute__((ext_vector_type(4)));
typedef float  f32x16 __attribute__((ext_vector_type(16)));
typedef float  f32x4v __attribute__((ext_vector_type(4)));

// async global->LDS, 16B per lane, wave-uniform LDS base + lane*16
__device__ __forceinline__ void gload_lds16(const void* g, void* lds) {
  __builtin_amdgcn_global_load_lds(
      (__attribute__((address_space(1))) void*)(uintptr_t)g,
      (__attribute__((address_space(3))) void*)lds,
      16, 0, 0);
}

// ---------------- fused input prep ----------------
// One kernel, blockIdx-range dispatch:
//  [0, 8192)        : x f32 -> bf16 (4 elem/thread)
//  [8192, 11264)    : w_in  [1024][3072] -> w_in^T  bf16 (32x32 tiles)
//  [11264, 12288)   : w_out [1024][1024] -> w_out^T bf16

__global__ __launch_bounds__(256) void prep_inputs(
    const float* __restrict__ x,     bf16* __restrict__ xb,
    const float* __restrict__ w_in,  bf16* __restrict__ wint,
    const float* __restrict__ w_out, bf16* __restrict__ woutt)
{
  __shared__ bf16 tile[32][33];
  const int bid = blockIdx.x, tid = threadIdx.x;

  if (bid < 8192) {
    int i = bid * 1024 + tid * 4;
    f32x4v v = *reinterpret_cast<const f32x4v*>(x + i);
    bf16x4 o;
    o[0] = (bf16)v[0]; o[1] = (bf16)v[1]; o[2] = (bf16)v[2]; o[3] = (bf16)v[3];
    *reinterpret_cast<bf16x4*>(xb + i) = o;
    return;
  }

  const float* in; bf16* out; int R, C, c0, r0;
  if (bid < 11264) {
    int t = bid - 8192;                 // 96 x 32 tiles
    in = w_in; out = wint; R = 1024; C = 3072;
    c0 = (t % 96) * 32; r0 = (t / 96) * 32;
  } else {
    int t = bid - 11264;                // 32 x 32 tiles
    in = w_out; out = woutt; R = 1024; C = 1024;
    c0 = (t % 32) * 32; r0 = (t / 32) * 32;
  }
  const int tx = tid & 31, ty = tid >> 5;
  #pragma unroll
  for (int i = ty; i < 32; i += 8)
    tile[i][tx] = (bf16)in[(size_t)(r0 + i) * C + (c0 + tx)];
  __syncthreads();
  #pragma unroll
  for (int i = ty; i < 32; i += 8)
    out[(size_t)(c0 + i) * R + (r0 + tx)] = tile[tx][i];
}

// ---------------- GEMM: C[M][N] = A[M][K] * Bt[N][K]^T (+bias) ----------------
// 128x128 tile, BK=64, 4 waves in 2x2, each wave 64x64 (4x4 16x16 fragments).
// Proven 2-barrier structure (bank conflicts 0). Deep-schedule ports CLOSED
// after 3 failures (R9/R14/R19, all ~75us): 1 block/CU at 128KB LDS means
// per-phase barriers stall the whole CU; 2+ co-resident 128^2 blocks absorb
// each other's drains (m114 overlap).
// L2-fit supertile order inside each XCD chunk (R21: GEMM1 FETCH 85->59MB,
// 67.6->65.7us - mechanism confirmed): working set of operand panels kept
// <= L2 so staging misses cost ~200cy (L2) not ~900cy (HBM) inside the
// exposed vmcnt drain. GEMM1 (nwgx=24): 4x6 supertiles (2.5MB). GEMM2
// (nwgx=8): 4x4 supertiles (2MB, was 8x8 linear = 4MB = borderline).
// BIAS path (GEMM2) uses non-temporal C stores (out is write-once).

template <typename OT, bool BIAS>
__global__ __launch_bounds__(256) void gemm_abt(
    const bf16* __restrict__ A,   // [M][K]
    const bf16* __restrict__ Bt,  // [N][K]
    const float* __restrict__ bias,
    OT* __restrict__ C, int M, int N, int K)
{
  __shared__ bf16 As[128 * 64];
  __shared__ bf16 Bs[128 * 64];

  const int tid = threadIdx.x;
  const int w = tid >> 6, l = tid & 63;
  const int l15 = l & 15, l4 = l >> 4, l7 = l & 7;
  const int wr = w >> 1, wc = w & 1;

  // XCD-chunked swizzle (grid%8==0, bijective) + L2-fit supertile order.
  const int nwgx = N >> 7;
  const int nwg  = (M >> 7) * nwgx;
  const int cpx  = nwg >> 3;
  const int bid  = blockIdx.x;
  const int cch  = bid & 7, lid = bid >> 3;
  int mrow, ncol;
  if (nwgx == 24) {                      // GEMM1: 64x24 grid, 8 rows/chunk
    const int st = lid / 24, t = lid % 24;      // 8 supertiles of 4x6
    mrow = cch * 8 + (st >> 2) * 4 + t / 6;
    ncol = (st & 3) * 6 + t % 6;
  } else if (nwgx == 8) {                // GEMM2: 64x8 grid, 8 rows/chunk
    const int st = lid / 16, t = lid % 16;      // 4 supertiles of 4x4
    mrow = cch * 8 + (st >> 1) * 4 + t / 4;
    ncol = (st & 1) * 4 + t % 4;
  } else {                               // generic linear chunk order
    const int swz = cch * cpx + lid;
    mrow = swz / nwgx; ncol = swz % nwgx;
  }
  const int m0 = mrow * 128, n0 = ncol * 128;

  f32x4 acc[4][4];
  #pragma unroll
  for (int i = 0; i < 4; i++)
    #pragma unroll
    for (int j = 0; j < 4; j++) acc[i][j] = (f32x4){0.f, 0.f, 0.f, 0.f};

  const int srow  = w * 8 + (l >> 3);
  const int sslot = (l & 7) ^ ((l >> 3) & 7);
  const int KT = K >> 6;

  for (int kt = 0; kt < KT; ++kt) {
    __syncthreads();
    const int kcol = kt * 64 + sslot * 8;
    #pragma unroll
    for (int p = 0; p < 4; ++p) {
      gload_lds16(A  + (size_t)(m0 + p * 32 + srow) * K + kcol,
                  (char*)As + p * 4096 + w * 1024);
      gload_lds16(Bt + (size_t)(n0 + p * 32 + srow) * K + kcol,
                  (char*)Bs + p * 4096 + w * 1024);
    }
    __syncthreads();

    #pragma unroll
    for (int kk = 0; kk < 2; ++kk) {
      const int coff = (kk * 32 + l4 * 8) ^ (l7 << 3);
      bf16x8 af[4], bq[4];
      #pragma unroll
      for (int m = 0; m < 4; ++m) {
        int r = wr * 64 + m * 16 + l15;
        af[m] = *reinterpret_cast<const bf16x8*>(&As[r * 64 + coff]);
      }
      #pragma unroll
      for (int n = 0; n < 4; ++n) {
        int r = wc * 64 + n * 16 + l15;
        bq[n] = *reinterpret_cast<const bf16x8*>(&Bs[r * 64 + coff]);
      }
      #pragma unroll
      for (int m = 0; m < 4; ++m)
        #pragma unroll
        for (int n = 0; n < 4; ++n)
          acc[m][n] = __builtin_amdgcn_mfma_f32_16x16x32_bf16(af[m], bq[n], acc[m][n], 0, 0, 0);
    }
  }

  #pragma unroll
  for (int m = 0; m < 4; ++m) {
    #pragma unroll
    for (int n = 0; n < 4; ++n) {
      int col = n0 + wc * 64 + n * 16 + l15;
      float bv = BIAS ? bias[col] : 0.f;
      #pragma unroll
      for (int j = 0; j < 4; ++j) {
        int row = m0 + wr * 64 + m * 16 + l4 * 4 + j;
        float v = acc[m][n][j] + bv;
        if constexpr (BIAS)
          __builtin_nontemporal_store((OT)v, &C[(size_t)row * N + col]);
        else
          C[(size_t)row * N + col] = (OT)v;
      }
    }
  }
}

// ---------------- fused flash attention (32x32x16, 8-wave shared K/V) ------
// EXACT R12/R16/R18/R20 structure - the measured optimum (3x reproduced).
// Restructure scorecard: dbuf (R7), in-reg P (R6), setprio (R10),
// V-prefetch (R15), KVBLK=128 (R17) - all negative. Occupancy-bound
// (VGPR 80, 3 blocks/CU at 48KB LDS); keep registers lean.

__global__ __launch_bounds__(512) void attn_fused(
    const bf16* __restrict__ qkv,
    bf16* __restrict__ aout)      // [8192][1024], col = h*64+d
{
  __shared__ bf16 Ks[64 * 64];      // [key][d], source-swizzled 16B slots
  __shared__ bf16 Vt[64 * 64];      // [d][key], slot = c ^ (d&7) ^ ((d>>3)&7)
  __shared__ bf16 Pl[8][32 * 64];   // per-wave P [q][key], slot = c ^ (q&7)

  const int tid = threadIdx.x;
  const int w = tid >> 6, l = tid & 63;
  const int l31 = l & 31, hi = l >> 5;

  // XCD-grouped swizzle: batch b lands entirely on XCD b (K/V L2 reuse)
  const int bid = blockIdx.x;            // 512 blocks
  const int c  = bid & 7, rr = bid >> 3;
  const int g  = c * 16 + (rr & 15);     // 0..127 = b*16+h
  const int qt = rr >> 4;                // 0..3
  const int h  = g & 15;
  const int b  = g >> 4;

  const bf16* base = qkv + (size_t)b * 1024 * 3072;
  const int qrow0 = qt * 256 + w * 32;

  const float qscale = 0.03125f * 1.44269504f;   // D^-0.5 * log2(e)
  bf16x8 qf[4];
  #pragma unroll
  for (int st = 0; st < 4; st++) {
    const bf16* p = base + (size_t)(qrow0 + l31) * 3072 + h * 64 + st * 16 + hi * 8;
    bf16x8 v = *reinterpret_cast<const bf16x8*>(p);
    #pragma unroll
    for (int e = 0; e < 8; e++) v[e] = (bf16)((float)v[e] * qscale);
    qf[st] = v;
  }

  bf16x8 onesf;
  #pragma unroll
  for (int e = 0; e < 8; e++) onesf[e] = (bf16)1.0f;

  f32x16 acc0 = {}, acc1 = {}, accS = {};

  const int skey  = w * 8 + (l >> 3);            // wave w stages rows w*8..w*8+7
  const int sslot = (l & 7) ^ ((l >> 3) & 7);
  const int vd0   = (tid & 15) * 4;
  const int vk0   = ((tid >> 4) & 15) * 4;
  const int vslot = (tid >> 5) & 7;
  const int vhalf = (tid >> 4) & 1;

  for (int kt = 0; kt < 16; ++kt) {
    __syncthreads();
    gload_lds16(base + (size_t)(kt * 64 + skey) * 3072 + 1024 + h * 64 + sslot * 8,
                (char*)Ks + w * 1024);
    if (tid < 256) {
      bf16x4 vv[4];
      #pragma unroll
      for (int i = 0; i < 4; ++i)
        vv[i] = *reinterpret_cast<const bf16x4*>(
            base + (size_t)(kt * 64 + vk0 + i) * 3072 + 2048 + h * 64 + vd0);
      #pragma unroll
      for (int j = 0; j < 4; ++j) {
        int d = vd0 + j;
        bf16x4 o; o[0] = vv[0][j]; o[1] = vv[1][j]; o[2] = vv[2][j]; o[3] = vv[3][j];
        *reinterpret_cast<bf16x4*>(
            &Vt[d * 64 + ((vslot ^ (d & 7) ^ ((d >> 3) & 7)) * 8 + vhalf * 4)]) = o;
      }
    }
    __syncthreads();

    #pragma unroll
    for (int ktile = 0; ktile < 2; ++ktile) {
      f32x16 s = {};
      const int key = ktile * 32 + l31;
      #pragma unroll
      for (int st = 0; st < 4; ++st) {
        const int slot = (2 * st + hi) ^ (key & 7);
        bf16x8 kf = *reinterpret_cast<const bf16x8*>(&Ks[key * 64 + slot * 8]);
        s = __builtin_amdgcn_mfma_f32_32x32x16_bf16(kf, qf[st], s, 0, 0, 0);
      }
      #pragma unroll
      for (int gq = 0; gq < 4; ++gq) {
        bf16x4 pb;
        #pragma unroll
        for (int j2 = 0; j2 < 4; ++j2) {
          float pv = __builtin_amdgcn_exp2f(s[4 * gq + j2]);
          pb[j2] = (bf16)pv;
        }
        const int chunk = ktile * 4 + gq;
        *reinterpret_cast<bf16x4*>(
            &Pl[w][l31 * 64 + ((chunk ^ (l31 & 7)) * 8 + hi * 4)]) = pb;
      }
    }

    const int d7x0 = (l31 & 7) ^ (l31 >> 3);
    const int d7x1 = d7x0 ^ 4;
    #pragma unroll
    for (int st = 0; st < 4; ++st) {
      const int cs = 2 * st + hi;
      bf16x8 pa  = *reinterpret_cast<const bf16x8*>(
          &Pl[w][l31 * 64 + ((cs ^ (l31 & 7)) * 8)]);
      accS = __builtin_amdgcn_mfma_f32_32x32x16_bf16(pa, onesf, accS, 0, 0, 0);
      bf16x8 vf0 = *reinterpret_cast<const bf16x8*>(
          &Vt[l31 * 64 + ((cs ^ d7x0) * 8)]);
      acc0 = __builtin_amdgcn_mfma_f32_32x32x16_bf16(pa, vf0, acc0, 0, 0, 0);
      bf16x8 vf1 = *reinterpret_cast<const bf16x8*>(
          &Vt[(32 + l31) * 64 + ((cs ^ d7x1) * 8)]);
      acc1 = __builtin_amdgcn_mfma_f32_32x32x16_bf16(pa, vf1, acc1, 0, 0, 0);
    }
  }

  #pragma unroll
  for (int reg = 0; reg < 16; ++reg) {
    int q_r = (reg & 3) + 8 * (reg >> 2) + 4 * hi;
    float rinv = 1.0f / accS[reg];
    size_t rowoff = ((size_t)b * 1024 + qrow0 + q_r) * 1024 + h * 64;
    aout[rowoff + l31]      = (bf16)(acc0[reg] * rinv);
    aout[rowoff + 32 + l31] = (bf16)(acc1[reg] * rinv);
  }
}

// ---------------- launch ----------------

extern "C" void kernel_launch(void* const* d_in, const int* in_sizes, int n_in,
                              void* d_out, int out_size, void* d_ws, size_t ws_size,
                              hipStream_t stream) {
  const float* x     = (const float*)d_in[0];   // [8,1024,1024]
  const float* w_in  = (const float*)d_in[1];   // [1024,3072]
  const float* w_out = (const float*)d_in[2];   // [1024,1024]
  const float* b_out = (const float*)d_in[3];   // [1024]
  float* out = (float*)d_out;                   // [8,1024,1024] fp32

  bf16* xb    = (bf16*)d_ws;                         // 8192*1024
  bf16* wint  = xb    + (size_t)8192 * 1024;         // 3072*1024  (w_in^T)
  bf16* woutt = wint  + (size_t)3072 * 1024;         // 1024*1024  (w_out^T)
  bf16* qkv   = woutt + (size_t)1024 * 1024;         // 8192*3072
  bf16* ao    = qkv   + (size_t)8192 * 3072;         // 8192*1024

  // fused input prep: x->bf16 + w_in^T + w_out^T in one launch
  prep_inputs<<<12288, 256, 0, stream>>>(x, xb, w_in, wint, w_out, woutt);

  // qkv = x @ w_in   (bf16 out) - 128^2, 1536 blocks, 4x6 supertiled swizzle
  gemm_abt<bf16, false><<<1536, 256, 0, stream>>>(xb, wint, nullptr, qkv, 8192, 3072, 1024);

  // fused attention -> ao (bf16, [token][h*64+d]) - 8-wave blocks, 512 total
  attn_fused<<<512, 512, 0, stream>>>(qkv, ao);

  // out = ao @ w_out + b_out   (fp32 out) - 128^2, 4x4 supertiled, NT stores
  gemm_abt<float, true><<<512, 256, 0, stream>>>(ao, woutt, b_out, out, 8192, 1024, 1024);
}